// Round 1
// baseline (415.434 us; speedup 1.0000x reference)
//
#include <hip/hip_runtime.h>
#include <hip/hip_bf16.h>
#include <stdint.h>

#define NN 4096
#define NF 128
#define NB 4

typedef __attribute__((ext_vector_type(4))) float  floatx4;
typedef __attribute__((ext_vector_type(8))) __bf16 bf16x8;

// ---------------------------------------------------------------------------
// Prep (unchanged, known-good): Xpack[b][kc][f][k8] = bf16(X[b][kc*32+k8][f]),
// wpack[kc2][n][k8] = bf16(w[kc2*32+k8][n]).  Frag(b,kc,nt) is 1KB contiguous.
// ---------------------------------------------------------------------------
__global__ __launch_bounds__(256) void prep_kernel(const float* __restrict__ X,
                                                   const float* __restrict__ w,
                                                   __bf16* __restrict__ Xpack,
                                                   __bf16* __restrict__ wpack) {
    __shared__ float Xs[32][129];
    const int tid = threadIdx.x;
    const int bx  = blockIdx.x;
    if (bx == 512) {  // wpack: tiny
        for (int p = tid; p < 512; p += 256) {
            int kc = p >> 7, n = p & 127;
#pragma unroll
            for (int k8 = 0; k8 < 32; k8 += 8) {
                bf16x8 v;
#pragma unroll
                for (int j = 0; j < 8; j++)
                    v[j] = (__bf16)w[(size_t)(kc * 32 + k8 + j) * NF + n];
                *(bf16x8*)(wpack + ((size_t)(kc * 128 + n)) * 32 + k8) = v;
            }
        }
        return;
    }
    const int b  = bx >> 7;
    const int kc = bx & 127;
    const float* Xt = X + ((size_t)b * NN + (size_t)kc * 32) * NF;
#pragma unroll
    for (int j = 0; j < 16; j++) {
        int i = tid + j * 256;           // coalesced
        Xs[i >> 7][i & 127] = Xt[i];
    }
    __syncthreads();
    const int f  = tid >> 1;
    const int kh = (tid & 1) * 16;
    bf16x8 v0, v1;
#pragma unroll
    for (int j = 0; j < 8; j++) v0[j] = (__bf16)Xs[kh + j][f];
#pragma unroll
    for (int j = 0; j < 8; j++) v1[j] = (__bf16)Xs[kh + 8 + j][f];
    __bf16* op = Xpack + (((size_t)b * 128 + kc) * 128 + f) * 32 + kh;
    *(bf16x8*)op = v0;
    *(bf16x8*)(op + 8) = v1;
}

// ---------------------------------------------------------------------------
// Main: barrier-free register streaming of A.
// Grid = 512 blocks (bijective XCD swizzle) x 256 thr (4 waves).
// Block = 32 rows: wave (rg,kq) = rows [m0+rg*16, +16) x k-half [kq*2048, +2048).
// Per k-chunk of 32: lane (quad,lm) loads A[row=lm][k=quad*8..+8] fp32 (2x16B,
// nontemporal), converts to the MFMA A-frag, row-sums for deg, and runs 8
// MFMAs against 1KB Xpack B-frags (L2-hot). No LDS / no syncthreads in the
// hot loop -> A loads stay in flight continuously (compiler-counted vmcnt).
// Epilogue: combine k-halves + deg via LDS, u=(ax+x)/deg -> bf16, u @ w, ReLU.
// ---------------------------------------------------------------------------
__global__ __launch_bounds__(256, 3) void main_kernel(const float* __restrict__ A,
                                                      const float* __restrict__ X,
                                                      const __bf16* __restrict__ Xpack,
                                                      const __bf16* __restrict__ wpack,
                                                      float* __restrict__ out) {
    __shared__ float  Pp[2][16][132];   // kq=1 partial acc
    __shared__ float  degp[2][16];      // kq=1 partial row-sums
    __shared__ __bf16 Us[32][136];      // u in bf16 for second GEMM

    const int tid  = threadIdx.x;
    const int wv   = tid >> 6;
    const int lane = tid & 63;
    const int lm   = lane & 15;
    const int quad = lane >> 4;
    const int rg   = wv & 1;        // 16-row group within block
    const int kq   = wv >> 1;       // k-half

    // bijective XCD swizzle: nwg=512 (%8==0), 64 consecutive tiles per XCD
    const int bid = blockIdx.x;
    const int swz = (bid & 7) * 64 + (bid >> 3);
    const int b   = swz >> 7;
    const int m0  = (swz & 127) << 5;

    const int row = m0 + rg * 16 + lm;
    const float*  Ap = A + ((size_t)b * NN + row) * NN + kq * 2048 + quad * 8;
    const __bf16* Bp = Xpack + (size_t)(b * 128 + kq * 64) * 4096 + lm * 32 + quad * 8;

    floatx4 acc[8];
#pragma unroll
    for (int nt = 0; nt < 8; nt++) acc[nt] = (floatx4){0.f, 0.f, 0.f, 0.f};
    floatx4 dsa = {0.f, 0.f, 0.f, 0.f}, dsb = {0.f, 0.f, 0.f, 0.f};

    // 1-deep A prefetch (HBM latency); B loaded in-iteration (L2-hot)
    floatx4 alo = __builtin_nontemporal_load((const floatx4*)Ap);
    floatx4 ahi = __builtin_nontemporal_load((const floatx4*)(Ap + 4));

#pragma unroll 4
    for (int kc = 0; kc < 64; kc++) {
        const __bf16* Bf = Bp + (size_t)kc * 4096;
        bf16x8 bf[8];
#pragma unroll
        for (int nt = 0; nt < 8; nt++)
            bf[nt] = *(const bf16x8*)(Bf + nt * 512);
        floatx4 nlo = alo, nhi = ahi;
        if (kc + 1 < 64) {
            const float* An = Ap + (size_t)(kc + 1) * 32;
            nlo = __builtin_nontemporal_load((const floatx4*)An);
            nhi = __builtin_nontemporal_load((const floatx4*)(An + 4));
        }
        dsa += alo; dsb += ahi;                      // deg row-sums (fp32)
        bf16x8 af;
#pragma unroll
        for (int i = 0; i < 4; i++) { af[i] = (__bf16)alo[i]; af[4 + i] = (__bf16)ahi[i]; }
#pragma unroll
        for (int nt = 0; nt < 8; nt++)
            acc[nt] = __builtin_amdgcn_mfma_f32_16x16x32_bf16(af, bf[nt], acc[nt], 0, 0, 0);
        alo = nlo; ahi = nhi;
    }

    // per-lane partial row-sum (row rg*16+lm, this k-half): combine quads
    float ds = dsa[0] + dsa[1] + dsa[2] + dsa[3] + dsb[0] + dsb[1] + dsb[2] + dsb[3];
    ds += __shfl_xor(ds, 16, 64);
    ds += __shfl_xor(ds, 32, 64);

    if (kq == 1) {
#pragma unroll
        for (int nt = 0; nt < 8; nt++)
#pragma unroll
            for (int i = 0; i < 4; i++)
                Pp[rg][quad * 4 + i][nt * 16 + lm] = acc[nt][i];
        if (quad == 0) degp[rg][lm] = ds;
    }
    __syncthreads();

    if (kq == 0) {
        float dsf = ds + degp[rg][lm];              // full row-sum, row rg*16+lm
        float deg[4];
#pragma unroll
        for (int i = 0; i < 4; i++) deg[i] = __shfl(dsf, quad * 4 + i, 64) + 1.0f;
        const float* Xb = X + ((size_t)b * NN + m0 + rg * 16) * NF;
#pragma unroll
        for (int nt = 0; nt < 8; nt++) {
            int col = nt * 16 + lm;
#pragma unroll
            for (int i = 0; i < 4; i++) {
                int r = quad * 4 + i;
                float u = (acc[nt][i] + Pp[rg][r][col] + Xb[(size_t)r * NF + col]) / deg[i];
                Us[rg * 16 + r][col] = (__bf16)u;
            }
        }
    }

    // w B-frags (L2-hot, independent of Us) — load before the barrier
    bf16x8 wf[4][4];
#pragma unroll
    for (int kc2 = 0; kc2 < 4; kc2++)
#pragma unroll
        for (int nt = 0; nt < 4; nt++)
            wf[kc2][nt] = *(const bf16x8*)(wpack +
                (size_t)(kc2 * 128 + kq * 64 + nt * 16 + lm) * 32 + quad * 8);
    __syncthreads();

    // z = u @ w (K=128); wave (rg,kq): rows rg*16..+16, cols kq*64..+64
    floatx4 z[4];
#pragma unroll
    for (int nt = 0; nt < 4; nt++) z[nt] = (floatx4){0.f, 0.f, 0.f, 0.f};
#pragma unroll
    for (int kc2 = 0; kc2 < 4; kc2++) {
        bf16x8 ua = *(const bf16x8*)&Us[rg * 16 + lm][kc2 * 32 + quad * 8];
#pragma unroll
        for (int nt = 0; nt < 4; nt++)
            z[nt] = __builtin_amdgcn_mfma_f32_16x16x32_bf16(ua, wf[kc2][nt], z[nt], 0, 0, 0);
    }
    float* ob = out + ((size_t)b * NN + m0 + rg * 16) * NF;
#pragma unroll
    for (int nt = 0; nt < 4; nt++) {
        int col = kq * 64 + nt * 16 + lm;
#pragma unroll
        for (int i = 0; i < 4; i++) {
            float v = z[nt][i];
            ob[(size_t)(quad * 4 + i) * NF + col] = v > 0.f ? v : 0.f;
        }
    }
}

extern "C" void kernel_launch(void* const* d_in, const int* in_sizes, int n_in,
                              void* d_out, int out_size, void* d_ws, size_t ws_size,
                              hipStream_t stream) {
    const float* A = (const float*)d_in[0];  // [4,4096,4096]
    const float* X = (const float*)d_in[1];  // [4,4096,128]
    const float* w = (const float*)d_in[2];  // [128,128]
    float* out = (float*)d_out;              // [4,4096,128]

    __bf16* Xpack = (__bf16*)d_ws;                 // 4 MB
    __bf16* wpack = Xpack + (size_t)NB * NF * NN;  // +32 KB

    prep_kernel<<<513, 256, 0, stream>>>(X, w, Xpack, wpack);
    main_kernel<<<512, 256, 0, stream>>>(A, X, Xpack, wpack, out);
}

// Round 2
// 391.477 us; speedup vs baseline: 1.0612x; 1.0612x over previous
//
#include <hip/hip_runtime.h>
#include <hip/hip_bf16.h>
#include <stdint.h>

#define NN 4096
#define NF 128
#define NB 4

typedef __attribute__((ext_vector_type(4))) float  floatx4;
typedef __attribute__((ext_vector_type(8))) __bf16 bf16x8;

// ---------------------------------------------------------------------------
// Prep (unchanged, known-good): Xpack[b][kc][f][k8] = bf16(X[b][kc*32+k8][f]),
// wpack[kc2][n][k8] = bf16(w[kc2*32+k8][n]).  Frag(b,kc,nt) is 1KB contiguous.
// ---------------------------------------------------------------------------
__global__ __launch_bounds__(256) void prep_kernel(const float* __restrict__ X,
                                                   const float* __restrict__ w,
                                                   __bf16* __restrict__ Xpack,
                                                   __bf16* __restrict__ wpack) {
    __shared__ float Xs[32][129];
    const int tid = threadIdx.x;
    const int bx  = blockIdx.x;
    if (bx == 512) {  // wpack: tiny
        for (int p = tid; p < 512; p += 256) {
            int kc = p >> 7, n = p & 127;
#pragma unroll
            for (int k8 = 0; k8 < 32; k8 += 8) {
                bf16x8 v;
#pragma unroll
                for (int j = 0; j < 8; j++)
                    v[j] = (__bf16)w[(size_t)(kc * 32 + k8 + j) * NF + n];
                *(bf16x8*)(wpack + ((size_t)(kc * 128 + n)) * 32 + k8) = v;
            }
        }
        return;
    }
    const int b  = bx >> 7;
    const int kc = bx & 127;
    const float* Xt = X + ((size_t)b * NN + (size_t)kc * 32) * NF;
#pragma unroll
    for (int j = 0; j < 16; j++) {
        int i = tid + j * 256;           // coalesced
        Xs[i >> 7][i & 127] = Xt[i];
    }
    __syncthreads();
    const int f  = tid >> 1;
    const int kh = (tid & 1) * 16;
    bf16x8 v0, v1;
#pragma unroll
    for (int j = 0; j < 8; j++) v0[j] = (__bf16)Xs[kh + j][f];
#pragma unroll
    for (int j = 0; j < 8; j++) v1[j] = (__bf16)Xs[kh + 8 + j][f];
    __bf16* op = Xpack + (((size_t)b * 128 + kc) * 128 + f) * 32 + kh;
    *(bf16x8*)op = v0;
    *(bf16x8*)(op + 8) = v1;
}

// ---------------------------------------------------------------------------
// Main v2: register streaming with a consistent-depth dual-stream pipeline.
// Grid = 512 blocks (XCD-swizzled) x 256 thr; block = 32 rows, 4 waves =
// 4 k-quarters (1024 k each = 32 chunks of K=32). 2 blocks/CU, 8 waves/CU.
// Per iter per wave: issue B(kc+1) [8x16B, L2-hot Xpack] then A(kc+2)
// [4x16B, nontemporal HBM]; consume A(kc)/B(kc) from registers. vmcnt FIFO:
// forcing B(kc) retires A(kc) (needed anyway) and leaves A(kc+1),B(kc+1),
// A(kc+2) in flight (~16KB/wave >> ~9KB/CU needed at 6.3TB/s * 900cy).
// Epilogue: 4 k-quarter partials + deg combined in LDS, u=(ax+x)/deg -> bf16,
// u @ w (K=128) per-wave 32-col slice, ReLU.
// ---------------------------------------------------------------------------
__global__ __launch_bounds__(256, 2) void main_kernel(const float* __restrict__ A,
                                                      const float* __restrict__ X,
                                                      const __bf16* __restrict__ Xpack,
                                                      const __bf16* __restrict__ wpack,
                                                      float* __restrict__ out) {
    __shared__ float  Pacc[3][32][132];  // waves 1..3 partial acc
    __shared__ float  degp[4][32];       // per-wave partial row-sums
    __shared__ __bf16 Us[32][136];       // u in bf16 for second GEMM

    const int tid  = threadIdx.x;
    const int kq   = tid >> 6;       // wave = k-quarter
    const int lane = tid & 63;
    const int lm   = lane & 15;
    const int quad = lane >> 4;

    // bijective XCD swizzle: nwg=512 (%8==0); each XCD gets 64 consecutive
    // tiles (same b, contiguous m) -> Xpack[b] (1MB) L2-resident per XCD
    const int bid = blockIdx.x;
    const int swz = (bid & 7) * 64 + (bid >> 3);
    const int b   = swz >> 7;
    const int m0  = (swz & 127) << 5;

    const float* Ap0 = A + ((size_t)b * NN + m0 + lm) * NN + kq * 1024 + quad * 8;
    const float* Ap1 = Ap0 + (size_t)16 * NN;
    const __bf16* Bp = Xpack + ((size_t)(b * 128 + kq * 32)) * 4096 + lm * 32 + quad * 8;

    floatx4 acc[2][8];
#pragma unroll
    for (int s = 0; s < 2; s++)
#pragma unroll
        for (int nt = 0; nt < 8; nt++) acc[s][nt] = (floatx4){0.f, 0.f, 0.f, 0.f};
    floatx4 sum0 = {0.f, 0.f, 0.f, 0.f}, sum1 = {0.f, 0.f, 0.f, 0.f};

    // prologue: A(0), A(1), B(0)  (issue order defines FIFO semantics)
    floatx4 a00 = __builtin_nontemporal_load((const floatx4*)Ap0);
    floatx4 a01 = __builtin_nontemporal_load((const floatx4*)(Ap0 + 4));
    floatx4 a10 = __builtin_nontemporal_load((const floatx4*)Ap1);
    floatx4 a11 = __builtin_nontemporal_load((const floatx4*)(Ap1 + 4));
    floatx4 n00 = __builtin_nontemporal_load((const floatx4*)(Ap0 + 32));
    floatx4 n01 = __builtin_nontemporal_load((const floatx4*)(Ap0 + 36));
    floatx4 n10 = __builtin_nontemporal_load((const floatx4*)(Ap1 + 32));
    floatx4 n11 = __builtin_nontemporal_load((const floatx4*)(Ap1 + 36));
    bf16x8 bc[8];
#pragma unroll
    for (int nt = 0; nt < 8; nt++) bc[nt] = *(const bf16x8*)(Bp + nt * 512);

    for (int kc = 0; kc < 32; kc++) {
        // issue next B then next-next A (clamped in-bounds; results unused
        // past the end, rotation discards them)
        const int kb = kc + 1 < 32 ? kc + 1 : 0;
        const int ka = kc + 2 < 32 ? kc + 2 : 0;
        bf16x8 bn[8];
        const __bf16* Bf = Bp + (size_t)kb * 4096;
#pragma unroll
        for (int nt = 0; nt < 8; nt++) bn[nt] = *(const bf16x8*)(Bf + nt * 512);
        const float* An0 = Ap0 + (size_t)ka * 32;
        const float* An1 = Ap1 + (size_t)ka * 32;
        floatx4 m00 = __builtin_nontemporal_load((const floatx4*)An0);
        floatx4 m01 = __builtin_nontemporal_load((const floatx4*)(An0 + 4));
        floatx4 m10 = __builtin_nontemporal_load((const floatx4*)An1);
        floatx4 m11 = __builtin_nontemporal_load((const floatx4*)(An1 + 4));

        // consume current (compiler inserts counted vmcnt, keeps newer loads
        // in flight)
        sum0 += a00 + a01;               // deg row-sums, row lm
        sum1 += a10 + a11;               // row lm+16
        bf16x8 af0, af1;
#pragma unroll
        for (int i = 0; i < 4; i++) { af0[i] = (__bf16)a00[i]; af0[4 + i] = (__bf16)a01[i]; }
#pragma unroll
        for (int i = 0; i < 4; i++) { af1[i] = (__bf16)a10[i]; af1[4 + i] = (__bf16)a11[i]; }
#pragma unroll
        for (int nt = 0; nt < 8; nt++) {
            acc[0][nt] = __builtin_amdgcn_mfma_f32_16x16x32_bf16(af0, bc[nt], acc[0][nt], 0, 0, 0);
            acc[1][nt] = __builtin_amdgcn_mfma_f32_16x16x32_bf16(af1, bc[nt], acc[1][nt], 0, 0, 0);
        }
        // rotate
        a00 = n00; a01 = n01; a10 = n10; a11 = n11;
        n00 = m00; n01 = m01; n10 = m10; n11 = m11;
#pragma unroll
        for (int nt = 0; nt < 8; nt++) bc[nt] = bn[nt];
    }

    // per-row k-quarter sums: combine quad phases (each quad holds 8 k/chunk)
    float ds0 = sum0[0] + sum0[1] + sum0[2] + sum0[3];
    float ds1 = sum1[0] + sum1[1] + sum1[2] + sum1[3];
    ds0 += __shfl_xor(ds0, 16, 64); ds0 += __shfl_xor(ds0, 32, 64);
    ds1 += __shfl_xor(ds1, 16, 64); ds1 += __shfl_xor(ds1, 32, 64);
    if (quad == 0) { degp[kq][lm] = ds0; degp[kq][16 + lm] = ds1; }

    if (kq) {
#pragma unroll
        for (int s = 0; s < 2; s++)
#pragma unroll
            for (int nt = 0; nt < 8; nt++)
#pragma unroll
                for (int i = 0; i < 4; i++)
                    Pacc[kq - 1][s * 16 + quad * 4 + i][nt * 16 + lm] = acc[s][nt][i];
    }

    // w B-frags (global, independent of LDS) — issue before the barrier
    bf16x8 wf[4][2];
#pragma unroll
    for (int kc2 = 0; kc2 < 4; kc2++)
#pragma unroll
        for (int nt = 0; nt < 2; nt++)
            wf[kc2][nt] = *(const bf16x8*)(wpack +
                (size_t)(kc2 * 128 + kq * 32 + nt * 16 + lm) * 32 + quad * 8);

    __syncthreads();

    if (kq == 0) {
        float degv[2][4];
#pragma unroll
        for (int s = 0; s < 2; s++)
#pragma unroll
            for (int i = 0; i < 4; i++) {
                int r = s * 16 + quad * 4 + i;
                degv[s][i] = degp[0][r] + degp[1][r] + degp[2][r] + degp[3][r] + 1.0f;
            }
        const float* Xb = X + ((size_t)b * NN + m0) * NF;
#pragma unroll
        for (int s = 0; s < 2; s++)
#pragma unroll
            for (int nt = 0; nt < 8; nt++)
#pragma unroll
                for (int i = 0; i < 4; i++) {
                    int r = s * 16 + quad * 4 + i, col = nt * 16 + lm;
                    float u = acc[s][nt][i] + Pacc[0][r][col] + Pacc[1][r][col] +
                              Pacc[2][r][col] + Xb[(size_t)r * NF + col];
                    Us[r][col] = (__bf16)(u / degv[s][i]);
                }
    }
    __syncthreads();

    // z = u @ w (K=128); wave kq: all 32 rows x cols [kq*32, +32)
    float* ob = out + ((size_t)b * NN + m0) * NF;
#pragma unroll
    for (int s = 0; s < 2; s++) {
        floatx4 z0 = {0.f, 0.f, 0.f, 0.f};
        floatx4 z1 = {0.f, 0.f, 0.f, 0.f};
#pragma unroll
        for (int kc2 = 0; kc2 < 4; kc2++) {
            bf16x8 ua = *(const bf16x8*)&Us[s * 16 + lm][kc2 * 32 + quad * 8];
            z0 = __builtin_amdgcn_mfma_f32_16x16x32_bf16(ua, wf[kc2][0], z0, 0, 0, 0);
            z1 = __builtin_amdgcn_mfma_f32_16x16x32_bf16(ua, wf[kc2][1], z1, 0, 0, 0);
        }
#pragma unroll
        for (int nt = 0; nt < 2; nt++) {
            int col = kq * 32 + nt * 16 + lm;
            floatx4 zv = nt ? z1 : z0;
#pragma unroll
            for (int i = 0; i < 4; i++) {
                int r = s * 16 + quad * 4 + i;
                float v = zv[i];
                ob[(size_t)r * NF + col] = v > 0.f ? v : 0.f;
            }
        }
    }
}

extern "C" void kernel_launch(void* const* d_in, const int* in_sizes, int n_in,
                              void* d_out, int out_size, void* d_ws, size_t ws_size,
                              hipStream_t stream) {
    const float* A = (const float*)d_in[0];  // [4,4096,4096]
    const float* X = (const float*)d_in[1];  // [4,4096,128]
    const float* w = (const float*)d_in[2];  // [128,128]
    float* out = (float*)d_out;              // [4,4096,128]

    __bf16* Xpack = (__bf16*)d_ws;                 // 4 MB
    __bf16* wpack = Xpack + (size_t)NB * NF * NN;  // +32 KB

    prep_kernel<<<513, 256, 0, stream>>>(X, w, Xpack, wpack);
    main_kernel<<<512, 256, 0, stream>>>(A, X, Xpack, wpack, out);
}